// Round 2
// baseline (530.508 us; speedup 1.0000x reference)
//
#include <hip/hip_runtime.h>

namespace {

constexpr int T_STEPS = 1000;
constexpr int NB      = 4096;
constexpr float LOG2E = 1.4426950408889634f;

__device__ __forceinline__ float fexp2(float x) { return __builtin_amdgcn_exp2f(x); }
__device__ __forceinline__ float frcp(float x)  { return __builtin_amdgcn_rcpf(x); }

// ds_swizzle BitMode: src_lane = ((lane & and) | or) ^ xor, per 32-lane half.
// offset = (xor<<10) | (or<<5) | and
template<int IMM>
__device__ __forceinline__ float swz(float v) {
    return __int_as_float(__builtin_amdgcn_ds_swizzle(__float_as_int(v), IMM));
}

// One element per 32 lanes (2 elements/wave, 2048 waves = 2 waves/SIMD).
// Lane q (0..31) owns gate row r = q of the 4H=32 gate vector: gate g=q>>3
// (0:i 1:f 2:g 3:o), unit u=q&7. All cross-lane traffic is ds_swizzle with
// immediate patterns (no addresses, no LDS storage, no barriers).
__global__ __launch_bounds__(256, 2)
void lstm_fused_kernel(
    const float* __restrict__ state, const float* __restrict__ dist,
    const float* __restrict__ e1W1, const float* __restrict__ e1b1,
    const float* __restrict__ e1W2, const float* __restrict__ e1b2,
    const float* __restrict__ e2W1, const float* __restrict__ e2b1,
    const float* __restrict__ e2W2, const float* __restrict__ e2b2,
    const float* __restrict__ Wih0, const float* __restrict__ Whh0,
    const float* __restrict__ bih0, const float* __restrict__ bhh0,
    const float* __restrict__ Wih1, const float* __restrict__ Whh1,
    const float* __restrict__ bih1, const float* __restrict__ bhh1,
    const float* __restrict__ decW, const float* __restrict__ decb,
    const float* __restrict__ finW, const float* __restrict__ finb,
    const float* __restrict__ fin2W, const float* __restrict__ fin2b,
    float* __restrict__ out)
{
    const int tid = (int)threadIdx.x;
    const int q   = tid & 31;                 // lane within element group
    const int n   = blockIdx.x * 8 + (tid >> 5);
    const int u   = q & 7;                    // unit
    const bool isG = ((q >> 3) == 2);         // this lane's gate uses tanh

    // ---- per-lane weight row r = q (stays in VGPRs) ----
    float wx0[8], wh0[8], wx1[8], wh1[8];
#pragma unroll
    for (int k = 0; k < 8; ++k) {
        wx0[k] = Wih0[q * 8 + k]; wh0[k] = Whh0[q * 8 + k];
        wx1[k] = Wih1[q * 8 + k]; wh1[k] = Whh1[q * 8 + k];
    }
    const float b0 = bih0[q] + bhh0[q];
    const float b1 = bih1[q] + bhh1[q];

    // decoder: lane holds dec row (q&3); head output (q&7): mu for u<4, sigma for u>=4
    float dwr[8];
#pragma unroll
    for (int k = 0; k < 8; ++k) dwr[k] = decW[(q & 3) * 8 + k];
    const float db = decb[q & 3];
    float fw[4]; float fb;
    {
        const float* Wp = (u < 4) ? finW : fin2W;
        const float* bp = (u < 4) ? finb : fin2b;
        const int oo = u & 3;
#pragma unroll
        for (int d = 0; d < 4; ++d) fw[d] = Wp[oo * 4 + d];
        fb = bp[oo];
    }

    // branchless activation constants (sigmoid vs tanh = 2*sig(2x)-1)
    const float scl = isG ? (-2.0f * LOG2E) : (-LOG2E);
    const float mul = isG ? 2.0f : 1.0f;
    const float add = isG ? -1.0f : 0.0f;

    // ---------------- encoders (one-time, replicated per lane) ----------------
    float h0[8], h1[8], c0, c1;
    {
        float s[16];
#pragma unroll
        for (int k = 0; k < 16; ++k) s[k] = state[n * 16 + k];
        float hm[4];
#pragma unroll
        for (int m = 0; m < 4; ++m) {
            float a = e1b1[m];
#pragma unroll
            for (int k = 0; k < 16; ++k) a = fmaf(s[k], e1W1[m * 16 + k], a);
            hm[m] = fmaxf(a, 0.0f);
        }
#pragma unroll
        for (int j = 0; j < 8; ++j) {
            float a = e1b2[j], b = e1b2[8 + j];
#pragma unroll
            for (int m = 0; m < 4; ++m) {
                a = fmaf(hm[m], e1W2[j * 4 + m], a);
                b = fmaf(hm[m], e1W2[(8 + j) * 4 + m], b);
            }
            h0[j] = fmaxf(a, 0.0f);   // layer0 h init
            h1[j] = fmaxf(b, 0.0f);   // layer1 h init
        }
#pragma unroll
        for (int m = 0; m < 4; ++m) {
            float a = e2b1[m];
#pragma unroll
            for (int k = 0; k < 16; ++k) a = fmaf(s[k], e2W1[m * 16 + k], a);
            hm[m] = fmaxf(a, 0.0f);
        }
        float a = e2b2[u], b = e2b2[8 + u];
#pragma unroll
        for (int m = 0; m < 4; ++m) {
            a = fmaf(hm[m], e2W2[u * 4 + m], a);
            b = fmaf(hm[m], e2W2[(8 + u) * 4 + m], b);
        }
        c0 = fmaxf(a, 0.0f);           // layer0 c (own unit, identical across gate copies)
        c1 = fmaxf(b, 0.0f);           // layer1 c
    }

    // ---------------- x stream + output pointer ----------------
    const float4* dp = reinterpret_cast<const float4*>(dist) + (size_t)n * 2;
    constexpr size_t TS4 = (size_t)NB * 2;   // float4 stride per timestep
    float* outp = out + ((u < 4) ? ((size_t)n * 4 + u)
                                 : ((size_t)T_STEPS * NB * 4 + (size_t)n * 4 + (u - 4)));
    const bool doStore = (q < 8);

    auto step = [&](const float4& lo, const float4& hi, float* op) {
        const float x[8] = {lo.x, lo.y, lo.z, lo.w, hi.x, hi.y, hi.z, hi.w};
        // ----- layer 0 (two independent 8-FMA chains) -----
        float ax = b0, ah = 0.0f;
#pragma unroll
        for (int k = 0; k < 8; ++k) { ax = fmaf(x[k], wx0[k], ax); ah = fmaf(h0[k], wh0[k], ah); }
        float a = ax + ah;
        float v = fmaf(frcp(1.0f + fexp2(a * scl)), mul, add);   // sig | tanh per gate
        float vi = swz<0x007>(v), vf = swz<0x107>(v), vg = swz<0x207>(v), vo = swz<0x307>(v);
        c0 = fmaf(vf, c0, vi * vg);
        float th = fmaf(frcp(1.0f + fexp2(c0 * (-2.0f * LOG2E))), 2.0f, -1.0f);
        float hu = vo * th;
        h0[0] = swz<0x00>(hu); h0[1] = swz<0x20>(hu); h0[2] = swz<0x40>(hu); h0[3] = swz<0x60>(hu);
        h0[4] = swz<0x80>(hu); h0[5] = swz<0xA0>(hu); h0[6] = swz<0xC0>(hu); h0[7] = swz<0xE0>(hu);
        // ----- layer 1 (h1-part first; h0-part consumes fresh broadcasts last) -----
        ax = b1; ah = 0.0f;
#pragma unroll
        for (int k = 0; k < 8; ++k) { ah = fmaf(h1[k], wh1[k], ah); ax = fmaf(h0[k], wx1[k], ax); }
        a = ax + ah;
        v = fmaf(frcp(1.0f + fexp2(a * scl)), mul, add);
        vi = swz<0x007>(v); vf = swz<0x107>(v); vg = swz<0x207>(v); vo = swz<0x307>(v);
        c1 = fmaf(vf, c1, vi * vg);
        th = fmaf(frcp(1.0f + fexp2(c1 * (-2.0f * LOG2E))), 2.0f, -1.0f);
        hu = vo * th;
        h1[0] = swz<0x00>(hu); h1[1] = swz<0x20>(hu); h1[2] = swz<0x40>(hu); h1[3] = swz<0x60>(hu);
        h1[4] = swz<0x80>(hu); h1[5] = swz<0xA0>(hu); h1[6] = swz<0xC0>(hu); h1[7] = swz<0xE0>(hu);
        // ----- decoder + heads -----
        float da = db;
#pragma unroll
        for (int k = 0; k < 8; ++k) da = fmaf(h1[k], dwr[k], da);
        da = fmaxf(da, 0.0f);
        const float d0 = swz<0x00>(da), d1 = swz<0x20>(da), d2 = swz<0x40>(da), d3 = swz<0x60>(da);
        float o = fb;
        o = fmaf(d0, fw[0], o); o = fmaf(d1, fw[1], o);
        o = fmaf(d2, fw[2], o); o = fmaf(d3, fw[3], o);
        if (doStore) *op = o;
    };

    // prologue: t=0,1 in regs; hot loop prefetches unconditionally (tail peeled)
    float4 xA0 = dp[0],   xA1 = dp[1];
    float4 xB0 = dp[TS4], xB1 = dp[TS4 + 1];
    const float4* pf = dp + 2 * TS4;

    for (int it = 0; it < (T_STEPS / 2) - 1; ++it) {
        float4 nA0 = pf[0], nA1 = pf[1];
        step(xA0, xA1, outp);
        outp += (size_t)NB * 4;
        float4 nB0 = pf[TS4], nB1 = pf[TS4 + 1];
        step(xB0, xB1, outp);
        outp += (size_t)NB * 4;
        xA0 = nA0; xA1 = nA1; xB0 = nB0; xB1 = nB1;
        pf += 2 * TS4;
    }
    step(xA0, xA1, outp);
    outp += (size_t)NB * 4;
    step(xB0, xB1, outp);
}

} // namespace

extern "C" void kernel_launch(void* const* d_in, const int* in_sizes, int n_in,
                              void* d_out, int out_size, void* d_ws, size_t ws_size,
                              hipStream_t stream) {
    const float* state = (const float*)d_in[0];
    const float* dist  = (const float*)d_in[1];
    const float* e1W1  = (const float*)d_in[2];
    const float* e1b1  = (const float*)d_in[3];
    const float* e1W2  = (const float*)d_in[4];
    const float* e1b2  = (const float*)d_in[5];
    const float* e2W1  = (const float*)d_in[6];
    const float* e2b1  = (const float*)d_in[7];
    const float* e2W2  = (const float*)d_in[8];
    const float* e2b2  = (const float*)d_in[9];
    const float* Wih0  = (const float*)d_in[10];
    const float* Whh0  = (const float*)d_in[11];
    const float* bih0  = (const float*)d_in[12];
    const float* bhh0  = (const float*)d_in[13];
    const float* Wih1  = (const float*)d_in[14];
    const float* Whh1  = (const float*)d_in[15];
    const float* bih1  = (const float*)d_in[16];
    const float* bhh1  = (const float*)d_in[17];
    const float* decW  = (const float*)d_in[18];
    const float* decb  = (const float*)d_in[19];
    const float* finW  = (const float*)d_in[20];
    const float* finb  = (const float*)d_in[21];
    const float* fin2W = (const float*)d_in[22];
    const float* fin2b = (const float*)d_in[23];
    float* outp = (float*)d_out;

    lstm_fused_kernel<<<dim3(NB / 8), dim3(256), 0, stream>>>(
        state, dist,
        e1W1, e1b1, e1W2, e1b2,
        e2W1, e2b1, e2W2, e2b2,
        Wih0, Whh0, bih0, bhh0,
        Wih1, Whh1, bih1, bhh1,
        decW, decb, finW, finb, fin2W, fin2b,
        outp);
}

// Round 3
// 446.006 us; speedup vs baseline: 1.1895x; 1.1895x over previous
//
#include <hip/hip_runtime.h>

namespace {

constexpr int T_STEPS = 1000;
constexpr int NB      = 4096;
constexpr float LOG2E = 1.4426950408889634f;

__device__ __forceinline__ float fexp2(float x) { return __builtin_amdgcn_exp2f(x); }
__device__ __forceinline__ float frcp(float x)  { return __builtin_amdgcn_rcpf(x); }

// DPP cross-lane on the VALU pipe (no LDS traffic, no lgkmcnt).
// row_ror:N (0x120|N): rotate within each 16-lane row. quad_perm: 0x00-0xFF.
template<int CTRL>
__device__ __forceinline__ float dppf(float v) {
    int i = __float_as_int(v);
    return __int_as_float(__builtin_amdgcn_update_dpp(i, i, CTRL, 0xF, 0xF, false));
}

// One element per 16 lanes (4 elements/wave, 1024 waves = 1/SIMD).
// Lane q: unit u=q&7, half hlf=q>>3. hlf0 computes rows (i_u,f_u), hlf1 (g_u,o_u).
// ALL cross-lane traffic is DPP; h lives register-rotated (slot j = unit (u+sgn*j)&7)
// with the weight layout permuted to match, so broadcasts become 7 rotations.
__global__ __launch_bounds__(256, 1)
void lstm_fused_kernel(
    const float* __restrict__ state, const float* __restrict__ dist,
    const float* __restrict__ e1W1, const float* __restrict__ e1b1,
    const float* __restrict__ e1W2, const float* __restrict__ e1b2,
    const float* __restrict__ e2W1, const float* __restrict__ e2b1,
    const float* __restrict__ e2W2, const float* __restrict__ e2b2,
    const float* __restrict__ Wih0, const float* __restrict__ Whh0,
    const float* __restrict__ bih0, const float* __restrict__ bhh0,
    const float* __restrict__ Wih1, const float* __restrict__ Whh1,
    const float* __restrict__ bih1, const float* __restrict__ bhh1,
    const float* __restrict__ decW, const float* __restrict__ decb,
    const float* __restrict__ finW, const float* __restrict__ finb,
    const float* __restrict__ fin2W, const float* __restrict__ fin2b,
    float* __restrict__ out)
{
    const int tid = (int)threadIdx.x;
    const int q   = tid & 15;
    const int n   = blockIdx.x * 16 + (tid >> 4);
    const int u   = q & 7;
    const int hlf = q >> 3;
    const int r0  = hlf * 16 + u;   // row of gate A (i_u | g_u)
    const int r1  = r0 + 8;         // row of gate B (f_u | o_u)

    // --- probe rotation direction once: hreg[j] = h[(u + sgn*j)&7] ---
    const int pv  = __builtin_amdgcn_update_dpp(0, q, 0x121 /*row_ror:1*/, 0xF, 0xF, true);
    const int sgn = (pv == ((q + 1) & 15)) ? 1 : -1;
    auto pidx = [&](int j) { return (u + sgn * j) & 7; };

    // activation constants; fold the exp2 input scale into the weights
    const float sA   = hlf ? (-2.0f * LOG2E) : (-LOG2E);   // tanh | sigmoid for row A
    const float sB   = -LOG2E;                              // rows B always sigmoid
    const float mulA = hlf ? 2.0f : 1.0f;
    const float addA = hlf ? -1.0f : 0.0f;

    // ---- per-lane weight rows; h-side permuted to the rotated register layout ----
    float wx0a[8], wh0a[8], wx0b[8], wh0b[8];
    float wx1a[8], wh1a[8], wx1b[8], wh1b[8];
#pragma unroll
    for (int k = 0; k < 8; ++k) {
        const int p = pidx(k);
        wx0a[k] = Wih0[r0 * 8 + k] * sA; wh0a[k] = Whh0[r0 * 8 + p] * sA;
        wx0b[k] = Wih0[r1 * 8 + k] * sB; wh0b[k] = Whh0[r1 * 8 + p] * sB;
        wx1a[k] = Wih1[r0 * 8 + p] * sA; wh1a[k] = Whh1[r0 * 8 + p] * sA;
        wx1b[k] = Wih1[r1 * 8 + p] * sB; wh1b[k] = Whh1[r1 * 8 + p] * sB;
    }
    const float b0a = (bih0[r0] + bhh0[r0]) * sA, b0b = (bih0[r1] + bhh0[r1]) * sB;
    const float b1a = (bih1[r0] + bhh1[r0]) * sA, b1b = (bih1[r1] + bhh1[r1]) * sB;

    // decoder: lane holds dec row dr=q&3 (h-permuted); head row oo=u&3 (mu u<4 | sigma u>=4)
    const int dr = q & 3;
    float dwr[8];
#pragma unroll
    for (int k = 0; k < 8; ++k) dwr[k] = decW[dr * 8 + pidx(k)];
    const float db = decb[dr];
    float fwp[4]; float fb;
    {
        const float* Wp = (u < 4) ? finW : fin2W;
        const float* bp = (u < 4) ? finb : fin2b;
        const int oo = u & 3;
#pragma unroll
        for (int j = 0; j < 4; ++j) fwp[j] = Wp[oo * 4 + ((dr + j) & 3)];
        fb = bp[oo];
    }

    // ---------------- encoders (one-time) ----------------
    float h0r[8], h1r[8], c0, c1;
    {
        float s[16];
#pragma unroll
        for (int k = 0; k < 16; ++k) s[k] = state[n * 16 + k];
        float hm1[4], hm2[4];
#pragma unroll
        for (int m = 0; m < 4; ++m) {
            float a = e1b1[m], b = e2b1[m];
#pragma unroll
            for (int k = 0; k < 16; ++k) {
                a = fmaf(s[k], e1W1[m * 16 + k], a);
                b = fmaf(s[k], e2W1[m * 16 + k], b);
            }
            hm1[m] = fmaxf(a, 0.0f); hm2[m] = fmaxf(b, 0.0f);
        }
#pragma unroll
        for (int j = 0; j < 8; ++j) {
            const int p = pidx(j);
            float a = e1b2[p], b = e1b2[8 + p];
#pragma unroll
            for (int m = 0; m < 4; ++m) {
                a = fmaf(hm1[m], e1W2[p * 4 + m], a);
                b = fmaf(hm1[m], e1W2[(8 + p) * 4 + m], b);
            }
            h0r[j] = fmaxf(a, 0.0f);   // layer0 h init (rotated layout)
            h1r[j] = fmaxf(b, 0.0f);   // layer1 h init
        }
        float a = e2b2[u], b = e2b2[8 + u];
#pragma unroll
        for (int m = 0; m < 4; ++m) {
            a = fmaf(hm2[m], e2W2[u * 4 + m], a);
            b = fmaf(hm2[m], e2W2[(8 + u) * 4 + m], b);
        }
        c0 = fmaxf(a, 0.0f);
        c1 = fmaxf(b, 0.0f);
    }

    // ---------------- x stream + output pointer ----------------
    const float4* dp = reinterpret_cast<const float4*>(dist) + (size_t)n * 2;
    constexpr size_t TS4 = (size_t)NB * 2;
    float* outp = out + ((u < 4) ? ((size_t)n * 4 + u)
                                 : ((size_t)T_STEPS * NB * 4 + (size_t)n * 4 + (u - 4)));
    const bool doStore = (q < 8);

    auto step = [&](const float4& lo, const float4& hi, float* op) {
        const float x[8] = {lo.x, lo.y, lo.z, lo.w, hi.x, hi.y, hi.z, hi.w};
        // ----- layer 0 -----
        float axa = b0a, aha = 0.0f, axb = b0b, ahb = 0.0f;
#pragma unroll
        for (int k = 0; k < 8; ++k) {
            axa = fmaf(x[k],   wx0a[k], axa); aha = fmaf(h0r[k], wh0a[k], aha);
            axb = fmaf(x[k],   wx0b[k], axb); ahb = fmaf(h0r[k], wh0b[k], ahb);
        }
        float a0 = fmaf(frcp(1.0f + fexp2(axa + aha)), mulA, addA); // sig(i) | tanh(g)
        float a1 = frcp(1.0f + fexp2(axb + ahb));                    // sig(f) | sig(o)
        float s0 = dppf<0x128>(a0);   // xor-8: tanh(g) | sig(i)
        float s1 = dppf<0x128>(a1);   // xor-8: sig(o)  | sig(f)
        float prod = a0 * s0;                       // sig(i)*tanh(g), both halves
        float fg = hlf ? s1 : a1, og = hlf ? a1 : s1;
        c0 = fmaf(fg, c0, prod);
        float th = fmaf(frcp(1.0f + fexp2(c0 * (-2.0f * LOG2E))), 2.0f, -1.0f);
        float hu = og * th;
        h0r[0] = hu;
        h0r[1] = dppf<0x121>(hu); h0r[2] = dppf<0x122>(hu); h0r[3] = dppf<0x123>(hu);
        h0r[4] = dppf<0x124>(hu); h0r[5] = dppf<0x125>(hu); h0r[6] = dppf<0x126>(hu);
        h0r[7] = dppf<0x127>(hu);
        // ----- layer 1 (input = fresh h0r; own-state part first) -----
        axa = b1a; aha = 0.0f; axb = b1b; ahb = 0.0f;
#pragma unroll
        for (int k = 0; k < 8; ++k) {
            aha = fmaf(h1r[k], wh1a[k], aha); axa = fmaf(h0r[k], wx1a[k], axa);
            ahb = fmaf(h1r[k], wh1b[k], ahb); axb = fmaf(h0r[k], wx1b[k], axb);
        }
        a0 = fmaf(frcp(1.0f + fexp2(axa + aha)), mulA, addA);
        a1 = frcp(1.0f + fexp2(axb + ahb));
        s0 = dppf<0x128>(a0);
        s1 = dppf<0x128>(a1);
        prod = a0 * s0;
        fg = hlf ? s1 : a1; og = hlf ? a1 : s1;
        c1 = fmaf(fg, c1, prod);
        th = fmaf(frcp(1.0f + fexp2(c1 * (-2.0f * LOG2E))), 2.0f, -1.0f);
        hu = og * th;
        h1r[0] = hu;
        h1r[1] = dppf<0x121>(hu); h1r[2] = dppf<0x122>(hu); h1r[3] = dppf<0x123>(hu);
        h1r[4] = dppf<0x124>(hu); h1r[5] = dppf<0x125>(hu); h1r[6] = dppf<0x126>(hu);
        h1r[7] = dppf<0x127>(hu);
        // ----- decoder + heads (quad_perm rotations, unambiguous) -----
        float da = db;
#pragma unroll
        for (int k = 0; k < 8; ++k) da = fmaf(h1r[k], dwr[k], da);
        da = fmaxf(da, 0.0f);
        const float d1 = dppf<0x39>(da);  // quad rotate 1: [1,2,3,0]
        const float d2 = dppf<0x4E>(da);  // quad rotate 2: [2,3,0,1]
        const float d3 = dppf<0x93>(da);  // quad rotate 3: [3,0,1,2]
        float o = fb;
        o = fmaf(da, fwp[0], o); o = fmaf(d1, fwp[1], o);
        o = fmaf(d2, fwp[2], o); o = fmaf(d3, fwp[3], o);
        if (doStore) *op = o;
    };

    // prologue: t=0,1 in regs; hot loop prefetches unconditionally (tail peeled)
    float4 xA0 = dp[0],   xA1 = dp[1];
    float4 xB0 = dp[TS4], xB1 = dp[TS4 + 1];
    const float4* pf = dp + 2 * TS4;

    for (int it = 0; it < (T_STEPS / 2) - 1; ++it) {
        float4 nA0 = pf[0], nA1 = pf[1];
        step(xA0, xA1, outp);
        outp += (size_t)NB * 4;
        float4 nB0 = pf[TS4], nB1 = pf[TS4 + 1];
        step(xB0, xB1, outp);
        outp += (size_t)NB * 4;
        xA0 = nA0; xA1 = nA1; xB0 = nB0; xB1 = nB1;
        pf += 2 * TS4;
    }
    step(xA0, xA1, outp);
    outp += (size_t)NB * 4;
    step(xB0, xB1, outp);
}

} // namespace

extern "C" void kernel_launch(void* const* d_in, const int* in_sizes, int n_in,
                              void* d_out, int out_size, void* d_ws, size_t ws_size,
                              hipStream_t stream) {
    const float* state = (const float*)d_in[0];
    const float* dist  = (const float*)d_in[1];
    const float* e1W1  = (const float*)d_in[2];
    const float* e1b1  = (const float*)d_in[3];
    const float* e1W2  = (const float*)d_in[4];
    const float* e1b2  = (const float*)d_in[5];
    const float* e2W1  = (const float*)d_in[6];
    const float* e2b1  = (const float*)d_in[7];
    const float* e2W2  = (const float*)d_in[8];
    const float* e2b2  = (const float*)d_in[9];
    const float* Wih0  = (const float*)d_in[10];
    const float* Whh0  = (const float*)d_in[11];
    const float* bih0  = (const float*)d_in[12];
    const float* bhh0  = (const float*)d_in[13];
    const float* Wih1  = (const float*)d_in[14];
    const float* Whh1  = (const float*)d_in[15];
    const float* bih1  = (const float*)d_in[16];
    const float* bhh1  = (const float*)d_in[17];
    const float* decW  = (const float*)d_in[18];
    const float* decb  = (const float*)d_in[19];
    const float* finW  = (const float*)d_in[20];
    const float* finb  = (const float*)d_in[21];
    const float* fin2W = (const float*)d_in[22];
    const float* fin2b = (const float*)d_in[23];
    float* outp = (float*)d_out;

    lstm_fused_kernel<<<dim3(NB / 16), dim3(256), 0, stream>>>(
        state, dist,
        e1W1, e1b1, e1W2, e1b2,
        e2W1, e2b1, e2W2, e2b2,
        Wih0, Whh0, bih0, bhh0,
        Wih1, Whh1, bih1, bhh1,
        decW, decb, finW, finb, fin2W, fin2b,
        outp);
}